// Round 10
// baseline (191.365 us; speedup 1.0000x reference)
//
#include <hip/hip_runtime.h>
#include <hip/hip_bf16.h>
#include <stdint.h>

typedef __attribute__((ext_vector_type(8))) short short8;
typedef __attribute__((ext_vector_type(4))) float f32x4;
typedef __attribute__((ext_vector_type(16))) float f32x16;
typedef __attribute__((ext_vector_type(4))) unsigned short ushort4v;
typedef __attribute__((ext_vector_type(4))) unsigned int uint4v;

#define TT 2048
#define HH 16
#define CCdim 1024
#define BT 4096   // B*T
#define LOG2E 1.44269504088896f

// round-to-nearest-even f32 -> bf16 (matches jnp astype)
__device__ inline unsigned short f2bf(float f) {
  unsigned u = __float_as_uint(f);
  u += 0x7FFF + ((u >> 16) & 1);
  return (unsigned short)(u >> 16);
}
__device__ inline float bf2f(unsigned short s) {
  return __uint_as_float(((unsigned)s) << 16);
}
__device__ inline unsigned pack2(float a, float b) {
  return (unsigned)f2bf(a) | ((unsigned)f2bf(b) << 16);
}
// HW packed f32->bf16 (RNE), one VALU op for two values
__device__ inline unsigned cvtpk(float lo, float hi) {
  unsigned r;
  asm("v_cvt_pk_bf16_f32 %0, %1, %2" : "=v"(r) : "v"(lo), "v"(hi));
  return r;
}
// swap a's high 32 lanes with b's low 32 lanes (one VALU op).
// Only safe when a and b are guaranteed-distinct values (R4 bug: compiler
// may alias registers of equal values and the swap degenerates).
__device__ inline void plswap(unsigned &a, unsigned &b) {
  asm("v_permlane32_swap_b32 %0, %1" : "+v"(a), "+v"(b));
}

__device__ inline void gload16(const unsigned short* g, unsigned short* l) {
  __builtin_amdgcn_global_load_lds((const __attribute__((address_space(1))) void*)g,
                                   (__attribute__((address_space(3))) void*)l, 16, 0, 0);
}

// ---------------- prep: casts + bf16-rounded rope table ----------------
__global__ __launch_bounds__(256) void prep(const float* __restrict__ x, const float* __restrict__ wq,
                     const float* __restrict__ wk, const float* __restrict__ wv,
                     const float* __restrict__ wp, unsigned short* __restrict__ xb,
                     unsigned short* __restrict__ wqkv, unsigned short* __restrict__ wpb,
                     float2* __restrict__ tab) {
  long idx = (long)blockIdx.x * blockDim.x + threadIdx.x;
  const long NX = (long)BT * CCdim;        // 4194304
  const long NW = (long)CCdim * CCdim;     // 1048576
  if (idx < NX) { xb[idx] = f2bf(x[idx]); return; }
  idx -= NX;
  if (idx < NW) { wqkv[idx] = f2bf(wq[idx]); return; }
  idx -= NW;
  if (idx < NW) { wqkv[NW + idx] = f2bf(wk[idx]); return; }
  idx -= NW;
  if (idx < NW) { wqkv[2 * NW + idx] = f2bf(wv[idx]); return; }
  idx -= NW;
  if (idx < NW) { wpb[idx] = f2bf(wp[idx]); return; }
  idx -= NW;
  if (idx < (long)TT * 32) {
    int t = (int)(idx >> 5), i = (int)(idx & 31);
    float invf = powf(10000.0f, -(float)i / 32.0f);
    float a = (float)t * invf;
    tab[idx] = make_float2(bf2f(f2bf(cosf(a))), bf2f(f2bf(sinf(a))));
  }
}

// ---------------- GEMM: C[m][n] = sum_k A[m][k] * W[n][k]; f32 or bf16 out ----
__global__ __launch_bounds__(256) void gemm_bt(const unsigned short* __restrict__ A,
                                               const unsigned short* __restrict__ W,
                                               void* __restrict__ C, int ldc, int obf16) {
  __shared__ __align__(16) unsigned short As[128 * 32];
  __shared__ __align__(16) unsigned short Ws[128 * 32];
  const int K = 1024;
  const int tid = threadIdx.x;
  const int lane = tid & 63;
  const int wid = tid >> 6;
  const int wr = wid >> 1, wc = wid & 1;
  const int m0 = blockIdx.y * 128;
  const int n0 = blockIdx.x * 128;

  f32x4 acc[4][4] = {};

  const int srow0 = tid >> 2;
  const int cgrp = tid & 3;
  const int cd = (cgrp ^ ((srow0 >> 1) & 3)) * 8;
  const unsigned short* Arow0 = A + (long)(m0 + srow0) * K + cd;
  const unsigned short* Arow1 = A + (long)(m0 + srow0 + 64) * K + cd;
  const unsigned short* Wrow0 = W + (long)(n0 + srow0) * K + cd;
  const unsigned short* Wrow1 = W + (long)(n0 + srow0 + 64) * K + cd;
  unsigned short* ldsA0 = As + wid * 512;
  unsigned short* ldsA1 = As + 2048 + wid * 512;
  unsigned short* ldsW0 = Ws + wid * 512;
  unsigned short* ldsW1 = Ws + 2048 + wid * 512;

  for (int kt = 0; kt < 32; ++kt) {
    const int kof = kt * 32;
    gload16(Arow0 + kof, ldsA0);
    gload16(Arow1 + kof, ldsA1);
    gload16(Wrow0 + kof, ldsW0);
    gload16(Wrow1 + kof, ldsW1);
    asm volatile("s_waitcnt vmcnt(0)" ::: "memory");
    __syncthreads();
    short8 af[4], bf[4];
#pragma unroll
    for (int mi = 0; mi < 4; ++mi) {
      int r = wr * 64 + mi * 16 + (lane & 15);
      af[mi] = *(const short8*)&As[r * 32 + (((lane >> 4) ^ ((r >> 1) & 3)) * 8)];
    }
#pragma unroll
    for (int nj = 0; nj < 4; ++nj) {
      int r = wc * 64 + nj * 16 + (lane & 15);
      bf[nj] = *(const short8*)&Ws[r * 32 + (((lane >> 4) ^ ((r >> 1) & 3)) * 8)];
    }
#pragma unroll
    for (int mi = 0; mi < 4; ++mi)
#pragma unroll
      for (int nj = 0; nj < 4; ++nj)
        acc[mi][nj] = __builtin_amdgcn_mfma_f32_16x16x32_bf16(af[mi], bf[nj], acc[mi][nj], 0, 0, 0);
    __syncthreads();
  }
#pragma unroll
  for (int mi = 0; mi < 4; ++mi)
#pragma unroll
    for (int nj = 0; nj < 4; ++nj)
#pragma unroll
      for (int j = 0; j < 4; ++j) {
        int rr = m0 + wr * 64 + mi * 16 + 4 * (lane >> 4) + j;
        int ncol = n0 + wc * 64 + nj * 16 + (lane & 15);
        if (obf16) ((unsigned short*)C)[(long)rr * ldc + ncol] = f2bf(acc[mi][nj][j]);
        else       ((float*)C)[(long)rr * ldc + ncol] = acc[mi][nj][j];
      }
}

// ---------------- RMSNorm + RoPE on q,k (bf16 in); Q carries log2e/8 scale ----
// Kp layout: [bh][tile(64)][c(4)][lane(64)][8]
__global__ __launch_bounds__(256) void rmsrope(const unsigned short* __restrict__ qkvb,
                                               const float* __restrict__ g,
                                               const float2* __restrict__ tab,
                                               unsigned short* __restrict__ Qh,
                                               unsigned short* __restrict__ Kp) {
  int rid = blockIdx.x * 4 + (threadIdx.x >> 6);  // (b*T + t)*H + h
  int lane = threadIdx.x & 63;
  int h = rid & 15;
  int bt = rid >> 4;
  int t = bt & (TT - 1);
  int b = bt >> 11;
  const unsigned short* src = qkvb + (long)bt * 3072;
  float2 cs = tab[t * 32 + (lane & 31)];
  float gg = g[lane];
  float sgn = (lane < 32) ? 1.0f : -1.0f;
  int bh = b * 16 + h;
  long qdst = ((long)bh * TT + t) * 64 + lane;
  long kdst = (((long)bh * 64 + (t >> 5)) * 4 + (lane >> 4)) * 512
            + ((t & 31) + 32 * ((lane >> 3) & 1)) * 8 + (lane & 7);
#pragma unroll
  for (int qk = 0; qk < 2; ++qk) {
    float u = bf2f(src[qk * 1024 + h * 64 + lane]);
    float ss = u * u;
    ss += __shfl_xor(ss, 1);  ss += __shfl_xor(ss, 2);  ss += __shfl_xor(ss, 4);
    ss += __shfl_xor(ss, 8);  ss += __shfl_xor(ss, 16); ss += __shfl_xor(ss, 32);
    float r = rsqrtf(ss * (1.0f / 64.0f) + 1e-5f);
    float xn = u * r * gg;
    float pr = __shfl_xor(xn, 32);
    float out = xn * cs.x + sgn * pr * cs.y;
    if (qk == 0) Qh[qdst] = f2bf(out * (0.125f * LOG2E));  // exp2-domain scores
    else         Kp[kdst] = f2bf(out);
  }
}

// ---------------- V repack: bf16 qkv (cols 2048..3071) -> fragment-packed Vp ----
// Vp layout: [bh][tile(64)][side(2)][c(2)][lane(64)][8]
__global__ __launch_bounds__(256) void vrepack(const unsigned short* __restrict__ qkvb,
                                               unsigned short* __restrict__ Vp) {
  __shared__ __align__(16) unsigned short S[64][72];
  int blk = blockIdx.x;          // bh*32 + tt64
  int bh = blk >> 5;
  int tt64 = blk & 31;
  int b = bh >> 4, h = bh & 15;
  int tid = threadIdx.x;
#pragma unroll
  for (int pass = 0; pass < 4; ++pass) {
    int tl = pass * 16 + (tid >> 4);
    int cg = tid & 15;
    ushort4v v = *(const ushort4v*)&qkvb[(long)(b * TT + tt64 * 64 + tl) * 3072 + 2048 + h * 64 + cg * 4];
    *(ushort4v*)&S[tl][cg * 4] = v;
  }
  __syncthreads();
  unsigned short* base = Vp + ((long)bh * 64 + tt64 * 2) * 2048;
#pragma unroll
  for (int part = 0; part < 2; ++part) {
    int id = part * 256 + tid;
    int l = id & 63;
    int c = (id >> 6) & 1;
    int s = (id >> 7) & 1;
    int ttloc = (id >> 8) & 1;
    int d = s * 32 + (l & 31);
    int t0 = ttloc * 32 + c * 16 + (l >> 5) * 8;
    short8 o;
#pragma unroll
    for (int j = 0; j < 8; ++j) o[j] = (short)S[t0 + j][d];
    *(short8*)(base + (long)id * 8) = o;
  }
}

// ---------------- flash attention, KV-split x2, fragment-packed K/V ----
// Shift-free softmax (scores pre-scaled to exp2 domain, |s'|<=11.8 so
// p<=3500 is f32/bf16-safe); ell computed on the MFMA pipe via all-ones
// A-fragment (every output row = sum_k P[k][q]).
__global__ __launch_bounds__(256, 4) void attn(const unsigned short* __restrict__ Qh,
                                               const unsigned short* __restrict__ Kp,
                                               const unsigned short* __restrict__ Vp,
                                               float* __restrict__ Opart,
                                               float* __restrict__ L) {
  const int lane = threadIdx.x & 63;
  const int wid = threadIdx.x >> 6;
  int bid = blockIdx.x;
  bid = (bid & 7) * 128 + (bid >> 3);       // XCD swizzle (1024 % 8 == 0: bijective)
  const int w = bid * 4 + wid;              // 0..4095
  const int qt = w & 63;
  const int half = (w >> 6) & 1;
  const int bh = w >> 7;                    // 0..31
  const long bhT = (long)bh * TT;
  const int q0 = qt * 32;
  const int l31 = lane & 31;
  const int hk = (lane >> 5) * 8;

  short8 qf[4];
  {
    const unsigned short* qp = Qh + (bhT + q0 + l31) * 64 + hk;
#pragma unroll
    for (int c = 0; c < 4; ++c) qf[c] = *(const short8*)(qp + c * 16);
  }

  const unsigned short* kp = Kp + ((long)(bh * 64 + half * 32)) * 2048 + lane * 8;
  const unsigned short* vp = Vp + ((long)(bh * 64 + half * 32)) * 2048 + lane * 8;

  f32x16 oacc0 = {}, oacc1 = {}, ellacc = {};
  short8 ones;
#pragma unroll
  for (int j = 0; j < 8; ++j) ones[j] = (short)0x3F80;   // bf16 1.0

  short8 kf[4];
#pragma unroll
  for (int c = 0; c < 4; ++c) kf[c] = *(const short8*)(kp + c * 512);

  for (int t = 0; t < 32; ++t) {
    short8 vf0[2], vf1[2];
#pragma unroll
    for (int c = 0; c < 2; ++c) {
      vf0[c] = *(const short8*)(vp + t * 2048 + c * 512);
      vf1[c] = *(const short8*)(vp + t * 2048 + 1024 + c * 512);
    }
    // S'^T[k][q] (exp2 domain): lane q=l31, k=(reg&3)+8*(reg>>2)+4*(lane>>5)
    __builtin_amdgcn_s_setprio(1);
    f32x16 s = {};
#pragma unroll
    for (int c = 0; c < 4; ++c)
      s = __builtin_amdgcn_mfma_f32_32x32x16_bf16(kf[c], qf[c], s, 0, 0, 0);
    __builtin_amdgcn_s_setprio(0);
    {
      int tn = (t < 31) ? (t + 1) : 31;
      const unsigned short* kpn = kp + tn * 2048;
#pragma unroll
      for (int c = 0; c < 4; ++c) kf[c] = *(const short8*)(kpn + c * 512);
    }

    // p = exp2(s'), no shift, no max, no sum tree
#pragma unroll
    for (int r = 0; r < 16; ++r) s[r] = exp2f(s[r]);

    unsigned a0 = cvtpk(s[0], s[1]),   a1 = cvtpk(s[2], s[3]);
    unsigned a2 = cvtpk(s[4], s[5]),   a3 = cvtpk(s[6], s[7]);
    unsigned a4 = cvtpk(s[8], s[9]),   a5 = cvtpk(s[10], s[11]);
    unsigned a6 = cvtpk(s[12], s[13]), a7 = cvtpk(s[14], s[15]);
    plswap(a0, a2); plswap(a1, a3); plswap(a4, a6); plswap(a5, a7);
    uint4v f0 = { a0, a1, a2, a3 };
    uint4v f1 = { a4, a5, a6, a7 };
    short8 pf0 = __builtin_bit_cast(short8, f0);
    short8 pf1 = __builtin_bit_cast(short8, f1);

    // O^T[d][q] += V^T[d][k] P^T[k][q];  ell[q] += sum_k P^T[k][q]
    __builtin_amdgcn_s_setprio(1);
    oacc0 = __builtin_amdgcn_mfma_f32_32x32x16_bf16(vf0[0], pf0, oacc0, 0, 0, 0);
    oacc0 = __builtin_amdgcn_mfma_f32_32x32x16_bf16(vf0[1], pf1, oacc0, 0, 0, 0);
    oacc1 = __builtin_amdgcn_mfma_f32_32x32x16_bf16(vf1[0], pf0, oacc1, 0, 0, 0);
    oacc1 = __builtin_amdgcn_mfma_f32_32x32x16_bf16(vf1[1], pf1, oacc1, 0, 0, 0);
    ellacc = __builtin_amdgcn_mfma_f32_32x32x16_bf16(ones, pf0, ellacc, 0, 0, 0);
    ellacc = __builtin_amdgcn_mfma_f32_32x32x16_bf16(ones, pf1, ellacc, 0, 0, 0);
    __builtin_amdgcn_s_setprio(0);
  }

  const long prow = (long)(half * 32 + bh) * TT + q0 + l31;
  float* orow = Opart + prow * 64;
  const int dhalf = 4 * (lane >> 5);
#pragma unroll
  for (int i = 0; i < 8; ++i) {
    int d = (2 * i & 3) + 8 * (i >> 1) + dhalf;
    *(float2*)&orow[d]      = make_float2(oacc0[2 * i], oacc0[2 * i + 1]);
    *(float2*)&orow[32 + d] = make_float2(oacc1[2 * i], oacc1[2 * i + 1]);
  }
  if (lane < 32) L[prow] = ellacc[0];   // all rows equal: sum_k P[k][q]
}

// ---------------- combine the two KV-half partials -> Y bf16 ----------------
__global__ __launch_bounds__(256) void combine(const float* __restrict__ Opart,
                                               const float* __restrict__ L,
                                               unsigned short* __restrict__ Y) {
  const long HALF = (long)32 * TT * 64;     // 4194304
  int idx = blockIdx.x * 256 + threadIdx.x; // 2M threads: row*32 + dpair
  int row = idx >> 5;                       // 0..65535 = bh*2048 + qrow
  int d = (idx & 31) * 2;
  float2 o0 = *(const float2*)&Opart[(long)row * 64 + d];
  float2 o1 = *(const float2*)&Opart[HALF + (long)row * 64 + d];
  float rinv = 1.0f / (L[row] + L[65536 + row]);
  float ox = (o0.x + o1.x) * rinv;
  float oy = (o0.y + o1.y) * rinv;
  int bh = row >> 11, qrow = row & (TT - 1);
  int b = bh >> 4, h = bh & 15;
  *(unsigned*)&Y[((long)(b * TT + qrow)) * CCdim + h * 64 + d] = pack2(ox, oy);
}

extern "C" void kernel_launch(void* const* d_in, const int* in_sizes, int n_in,
                              void* d_out, int out_size, void* d_ws, size_t ws_size,
                              hipStream_t stream) {
  const float* x  = (const float*)d_in[0];
  const float* wq = (const float*)d_in[1];
  const float* wk = (const float*)d_in[2];
  const float* wv = (const float*)d_in[3];
  const float* wp = (const float*)d_in[4];
  const float* g  = (const float*)d_in[5];

  char* w = (char*)d_ws;
  unsigned short* qkvb = (unsigned short*)w; w += (long)BT * 3 * CCdim * 2;   // 24 MB
  unsigned short* xb   = (unsigned short*)w; w += (long)BT * CCdim * 2;       // 8 MB
  unsigned short* wqkv = (unsigned short*)w; w += (long)3 * CCdim * CCdim * 2; // 6 MB
  unsigned short* wpb  = (unsigned short*)w; w += (long)CCdim * CCdim * 2;    // 2 MB
  unsigned short* qh   = (unsigned short*)w; w += (long)BT * CCdim * 2;
  unsigned short* kp   = (unsigned short*)w; w += (long)BT * CCdim * 2;
  unsigned short* vp   = (unsigned short*)w; w += (long)BT * CCdim * 2;
  unsigned short* yb   = (unsigned short*)w; w += (long)BT * CCdim * 2;
  float2* tab          = (float2*)w;         w += (long)TT * 32 * 8;

  // attn partials overlay qkvb+xb+wqkv (38 MB, all dead by attn): 33.5+0.25 MB
  float* Opart = (float*)qkvb;
  float* Lbuf  = (float*)qkvb + 8388608;

  long total = (long)BT * CCdim + 4L * CCdim * CCdim + (long)TT * 32;
  int pblocks = (int)((total + 255) / 256);
  prep<<<pblocks, 256, 0, stream>>>(x, wq, wk, wv, wp, xb, wqkv, wpb, tab);
  gemm_bt<<<dim3(24, 32), 256, 0, stream>>>(xb, wqkv, qkvb, 3072, 1);
  rmsrope<<<16384, 256, 0, stream>>>(qkvb, g, tab, qh, kp);
  vrepack<<<1024, 256, 0, stream>>>(qkvb, vp);
  attn<<<1024, 256, 0, stream>>>(qh, kp, vp, Opart, Lbuf);
  combine<<<8192, 256, 0, stream>>>(Opart, Lbuf, yb);
  gemm_bt<<<dim3(8, 32), 256, 0, stream>>>(yb, wpb, d_out, 1024, 0);
}